// Round 13
// baseline (70.682 us; speedup 1.0000x reference)
//
#include <hip/hip_runtime.h>
#include <hip/hip_bf16.h>
#include <stdint.h>

#define BATCH 16384
#define INF   1024
#define OUTF  2048

#define BM 128
#define BN 128
#define BK 128
#define NT (INF / BK)   // 8 K-tiles

typedef unsigned char u8;
typedef unsigned int u32;
using i32x4  = __attribute__((ext_vector_type(4))) int;
using i32x8  = __attribute__((ext_vector_type(8))) int;
using f32x16 = __attribute__((ext_vector_type(16))) float;

// pack 4 f32 -> 4 OCP e4m3 bytes via HW cvt (RNE, saturating)
__device__ __forceinline__ u32 pk4_fp8(float a, float b, float c, float d) {
  int v = __builtin_amdgcn_cvt_pk_fp8_f32(a, b, 0, false);    // bytes 0,1
  v = __builtin_amdgcn_cvt_pk_fp8_f32(c, d, v, true);         // bytes 2,3
  return (u32)v;
}

__device__ __forceinline__ void load_lds16(const void* g, void* l) {
  __builtin_amdgcn_global_load_lds(
      (const __attribute__((address_space(1))) unsigned*)g,
      (__attribute__((address_space(3))) unsigned*)l, 16, 0, 0);
}

// ---- x: fp32 [BATCH][INF] -> fp8 e4m3 + EXACT fp32 row sum-of-squares ----
__global__ void __launch_bounds__(256) k_convert_x(const float* __restrict__ x,
                                                   u8* __restrict__ xb,
                                                   float* __restrict__ xsq) {
  const int row = blockIdx.x * 4 + (threadIdx.x >> 6);
  const int l = threadIdx.x & 63;
  const float* xr = x + (size_t)row * INF;
  u32* xbr = reinterpret_cast<u32*>(xb + (size_t)row * INF);
  float s = 0.f;
  #pragma unroll
  for (int i = 0; i < 4; ++i) {
    const float4 v = reinterpret_cast<const float4*>(xr)[l + i * 64];
    xbr[l + i * 64] = pk4_fp8(v.x, v.y, v.z, v.w);
    s += v.x * v.x + v.y * v.y + v.z * v.z + v.w * v.w;
  }
  #pragma unroll
  for (int off = 32; off > 0; off >>= 1) s += __shfl_xor(s, off, 64);
  if (l == 0) xsq[row] = s;
}

// ---- w: fp32 [INF][OUTF] -> fp8 w^T [OUTF][INF] + per-column sq-partials ----
__global__ void __launch_bounds__(256) k_convert_w(const float* __restrict__ w,
                                                   u8* __restrict__ wt,
                                                   float* __restrict__ part) {
  __shared__ float tile[64][65];
  __shared__ float psum[4][64];
  const int n0 = blockIdx.x * 64;   // along OUTF
  const int k0 = blockIdx.y * 64;   // along INF
  const int tid = threadIdx.x;
  const int c = tid & 63, r4 = tid >> 6;
  float s = 0.f;
  #pragma unroll
  for (int i = 0; i < 16; ++i) {
    int k = r4 + i * 4;
    float v = w[(size_t)(k0 + k) * OUTF + n0 + c];   // coalesced over n
    tile[k][c] = v;
    s += v * v;
  }
  psum[r4][c] = s;
  __syncthreads();
  #pragma unroll
  for (int i = 0; i < 4; ++i) {
    const int n = (tid >> 4) + i * 16;      // 0..63
    const int kq = (tid & 15) * 4;          // 0..60
    u32 p = pk4_fp8(tile[kq][n], tile[kq + 1][n], tile[kq + 2][n], tile[kq + 3][n]);
    *reinterpret_cast<u32*>(wt + (size_t)(n0 + n) * INF + k0 + kq) = p;
  }
  if (r4 == 0)
    part[(size_t)blockIdx.y * OUTF + n0 + c] =
        psum[0][c] + psum[1][c] + psum[2][c] + psum[3][c];
}

// ---- fused GEMM (MX-fp8, unit scales): out = xsq[row] + wsq[col] - 2*(x@w) ----
// R12 fp8 kernel + T4 counted-vmcnt double-buffer: 128x128 tile, 4 waves
// (2x2 of 64x64), BK=128 (NT=8). LDS 64 KiB = 2 buffers x (A 16K + B 16K);
// 2 blocks/CU. Prefetch 2 K-tiles deep; per tile wait vmcnt(8) (tile-t's 8
// loads done, t+1's 8 STAY IN FLIGHT - never drain to 0 mid-loop), compute,
// lgkmcnt(0)+barrier, stage t+2 into freed buffer. Removes the per-tile
// L3-latency drain that bounded R12.
// Swizzle byte(r,c) = r*128 + (c ^ ((r&7)<<4)), both-sides. MFMA:
// mfma_scale_f32_32x32x64_f8f6f4, E8M0 scale 0x7F = 1.0.
// C/D 32x32: col=lane&31, row=(reg&3)+8*(reg>>2)+4*(lane>>5).
__global__ void __launch_bounds__(256, 2) k_gemm(const u8* __restrict__ A,
                                                 const u8* __restrict__ Bt,
                                                 const float* __restrict__ xsq,
                                                 const float* __restrict__ prt,
                                                 float* __restrict__ out) {
  __shared__ __attribute__((aligned(16))) char lds[65536];

  const int tid = threadIdx.x;
  const int wave = tid >> 6, lane = tid & 63;
  const int bid = blockIdx.x;
  const int xcd = bid & 7;
  const int idx = bid >> 3;                // 0..255
  const int bxn = xcd * 2 + (idx & 1);     // 0..15  (N block, XCD-pinned pair)
  const int by  = idx >> 1;                // 0..127 (M block)
  const int rowBase = by * BM;
  const int colBase = bxn * BN;
  const int wr = (wave >> 1) & 1, wc = wave & 1;   // 2x2 waves of 64x64

  // staging: thread covers row srow(+32i), 16 fp8 bytes at pre-swizzled col
  const int srow = tid >> 3;                                      // 0..31
  const int ke   = ((tid & 7) * 16) ^ (((tid >> 3) & 7) << 4);    // byte col
  const u8* aS = A  + (size_t)(rowBase + srow) * INF + ke;
  const u8* bS = Bt + (size_t)(colBase + srow) * INF + ke;
  char* ldsw = lds + tid * 16;

  auto STAGE = [&](int parity, int t) {     // 8 issues/thread/tile
    const int kk = t * BK;
    char* dst = ldsw + parity * 32768;
    #pragma unroll
    for (int i = 0; i < 4; ++i)             // A rows [i*32, i*32+32)
      load_lds16(aS + (size_t)(i * 32) * INF + kk, dst + i * 4096);
    #pragma unroll
    for (int i = 0; i < 4; ++i)             // B rows
      load_lds16(bS + (size_t)(i * 32) * INF + kk, dst + 16384 + i * 4096);
  };

  // fragment read addressing
  const int r31 = lane & 31;
  const int kh  = lane >> 5;                 // k-half (0/1)
  const int swzr = (r31 & 7) << 4;           // row&7 (m*32, wr*64 mult of 8)
  const int aRd = (wr * 64 + r31) * 128;            // + m*4096
  const int bRd = 16384 + (wc * 64 + r31) * 128;    // + n*4096

  f32x16 acc[2][2] = {};
  const int SC = 0x7f7f7f7f;                 // E8M0 = 127 -> scale 1.0

  // prologue: 2 K-tiles in flight (16 loads/thread outstanding)
  STAGE(0, 0);
  STAGE(1, 1);

  #pragma unroll
  for (int t = 0; t < NT; ++t) {
    if (t < NT - 1) asm volatile("s_waitcnt vmcnt(8)" ::: "memory");  // t done, t+1 in flight
    else            asm volatile("s_waitcnt vmcnt(0)" ::: "memory");
    __builtin_amdgcn_s_barrier();            // buf[t&1] resident for all waves

    const char* buf = lds + (t & 1) * 32768;

    #pragma unroll
    for (int kc = 0; kc < 2; ++kc) {
      const int cb0 = (kc * 64 + kh * 32) ^ swzr;
      const int cb1 = (kc * 64 + kh * 32 + 16) ^ swzr;
      i32x8 a[2], b[2];
      #pragma unroll
      for (int m = 0; m < 2; ++m) {
        i32x4 lo = *reinterpret_cast<const i32x4*>(buf + aRd + m * 4096 + cb0);
        i32x4 hi = *reinterpret_cast<const i32x4*>(buf + aRd + m * 4096 + cb1);
        a[m] = __builtin_shufflevector(lo, hi, 0, 1, 2, 3, 4, 5, 6, 7);
      }
      #pragma unroll
      for (int n = 0; n < 2; ++n) {
        i32x4 lo = *reinterpret_cast<const i32x4*>(buf + bRd + n * 4096 + cb0);
        i32x4 hi = *reinterpret_cast<const i32x4*>(buf + bRd + n * 4096 + cb1);
        b[n] = __builtin_shufflevector(lo, hi, 0, 1, 2, 3, 4, 5, 6, 7);
      }
      __builtin_amdgcn_s_setprio(1);
      #pragma unroll
      for (int m = 0; m < 2; ++m)
        #pragma unroll
        for (int n = 0; n < 2; ++n)
          acc[m][n] = __builtin_amdgcn_mfma_scale_f32_32x32x64_f8f6f4(
              a[m], b[n], acc[m][n], 0, 0, 0, SC, 0, SC);
      __builtin_amdgcn_s_setprio(0);
    }

    asm volatile("s_waitcnt lgkmcnt(0)" ::: "memory");  // my reads of buf done
    __builtin_amdgcn_s_barrier();                        // all waves done reading
    if (t + 2 < NT) STAGE(t & 1, t + 2);                 // overwrite freed buffer
  }

  // ---- epilogue: wsq from partials via dead LDS, then fused write ----
  __syncthreads();                            // all waves done with A/B in LDS
  float* wlds = reinterpret_cast<float*>(lds);
  if (tid < BN) {
    float sw = 0.f;
    #pragma unroll
    for (int kb = 0; kb < 16; ++kb)
      sw += prt[(size_t)kb * OUTF + colBase + tid];
    wlds[tid] = sw;
  }
  __syncthreads();

  #pragma unroll
  for (int m = 0; m < 2; ++m) {
    #pragma unroll
    for (int reg = 0; reg < 16; ++reg) {
      const int rowf = (reg & 3) + 8 * (reg >> 2) + 4 * kh;
      const int row = rowBase + wr * 64 + m * 32 + rowf;
      const float xs = xsq[row];
      #pragma unroll
      for (int n = 0; n < 2; ++n) {
        const int col = colBase + wc * 64 + n * 32 + r31;
        out[(size_t)row * OUTF + col] = xs + wlds[wc * 64 + n * 32 + r31]
                                        - 2.0f * acc[m][n][reg];
      }
    }
  }
}

extern "C" void kernel_launch(void* const* d_in, const int* in_sizes, int n_in,
                              void* d_out, int out_size, void* d_ws, size_t ws_size,
                              hipStream_t stream) {
  const float* x = (const float*)d_in[0];
  const float* w = (const float*)d_in[1];
  float* out = (float*)d_out;

  char* ws = (char*)d_ws;
  u8* xb     = (u8*)(ws);                     // 16384*1024   = 16777216 B
  u8* wt     = (u8*)(ws + 16777216);          // 2048*1024    =  2097152 B (B^T fp8)
  float* xsq = (float*)(ws + 18874368);       // 16384*4      =    65536 B
  float* prt = (float*)(ws + 18939904);       // 16*2048*4    =   131072 B

  k_convert_x<<<BATCH / 4, 256, 0, stream>>>(x, xb, xsq);
  k_convert_w<<<dim3(OUTF / 64, INF / 64), 256, 0, stream>>>(w, wt, prt);
  k_gemm<<<(BATCH / BM) * (OUTF / BN), 256, 0, stream>>>(xb, wt, xsq, prt, out);
}